// Round 1
// baseline (490.228 us; speedup 1.0000x reference)
//
#include <hip/hip_runtime.h>
#include <hip/hip_cooperative_groups.h>

namespace cg = cooperative_groups;

#define N_NODES 10000
#define E_EDGES 640000
#define IN_CH   512
#define OUT_CH  256
#define HALF_CH 128
#define NPLANE  10240                           // per-XCD count/cursor plane stride (ints)
#define NCHUNK  40                              // ceil(10000/256) scan chunks
#define CSR_CAP (E_EDGES + 16 * N_NODES + 128)  // padded capacity + prefetch slack
#define G_GEMM_X 157                            // ceil(10000/64)
#define G_GEMM  (G_GEMM_X * 2)                  // x2 planes

typedef short bf16x8 __attribute__((ext_vector_type(8)));
typedef float f32x4  __attribute__((ext_vector_type(4)));

__device__ __forceinline__ unsigned short f2b(float f) {
    unsigned int u = __float_as_uint(f);
    return (unsigned short)((u + 0x7FFFu + ((u >> 16) & 1u)) >> 16);
}
__device__ __forceinline__ float lo16(unsigned int u) { return __uint_as_float(u << 16); }
__device__ __forceinline__ float hi16(unsigned int u) { return __uint_as_float(u & 0xFFFF0000u); }
__device__ __forceinline__ float b2f(unsigned short u) { return __uint_as_float(((unsigned int)u) << 16); }

// ---------------------------------------------------------------------------------
// Cooperative fused CSR-build + GEMM.
//   Phase A: per-XCD degree histogram (atomics XCD-local -> no cross-XCD line ping-pong)
//   Phase B: deterministic prefix-sum segment allocation + per-XCD cursor starts
//            + dinv/sq + pad sentinels (replaces alloc_kernel, no global counter atomic)
//   Phase C: scatter with IDENTICAL edge->thread mapping as phase A (block never
//            migrates, so per-(XCD,row) bumps exactly match counted capacity),
//            then blocks 0..G_GEMM-1 run the bf16 MFMA GEMM (unchanged core).
// Correctness does NOT depend on XCC_ID values being meaningful — only on a block
// reading the same value in A and C, which is trivially true (read once).
// ---------------------------------------------------------------------------------
__global__ __launch_bounds__(256) void fused_build_gemm(
        const float* __restrict__ x,
        const float* __restrict__ w,
        const float* __restrict__ bias,
        const int*   __restrict__ row,
        const int*   __restrict__ col,
        int*         __restrict__ cnt,        // [8][NPLANE] counts -> cursors (in place)
        int*         __restrict__ rowstart,   // [N] chunk-local exclusive prefix
        int*         __restrict__ chunksum,   // [NCHUNK]
        int2*        __restrict__ seg,
        float*       __restrict__ dinv,
        float*       __restrict__ sq,
        int*         __restrict__ csr_col,
        unsigned short* __restrict__ h0b) {
    __shared__ unsigned short As[64][72];
    __shared__ unsigned short Bs[128][72];
    cg::grid_group grid = cg::this_grid();
    const int tid = threadIdx.x;
    const int bid = blockIdx.x;
    const int gsz = gridDim.x * 256;

    unsigned int xcc;
    asm volatile("s_getreg_b32 %0, hwreg(HW_REG_XCC_ID)" : "=s"(xcc));
    int* mycnt = cnt + (size_t)(xcc & 7) * NPLANE;

    // ---- Phase A: XCD-local degree histogram ----
    for (int e = bid * 256 + tid; e < E_EDGES; e += gsz)
        atomicAdd(&mycnt[row[e]], 1);
    grid.sync();

    // ---- Phase B1: per-chunk inclusive scan of padded degrees (40 blocks) ----
    int* s_scan = (int*)&As[0][0];  // 256 ints, aliases GEMM LDS (phases are fenced)
    if (bid < NCHUNK) {
        int r = bid * 256 + tid;
        int pad = 0;
        if (r < N_NODES) {
            int d = 0;
            #pragma unroll
            for (int p8 = 0; p8 < 8; p8++) d += cnt[p8 * NPLANE + r];
            pad = (d + 15) & ~15;
        }
        s_scan[tid] = pad;
        __syncthreads();
        for (int off = 1; off < 256; off <<= 1) {
            int v = (tid >= off) ? s_scan[tid - off] : 0;
            __syncthreads();
            s_scan[tid] += v;
            __syncthreads();
        }
        if (r < N_NODES) rowstart[r] = s_scan[tid] - pad;  // exclusive within chunk
        if (tid == 255) chunksum[bid] = s_scan[255];
    }
    grid.sync();

    // ---- Phase B3: chunk bases (wave-0 scan, redundant per block) + finalize rows ----
    int* s_cb = (int*)&Bs[0][0];  // NCHUNK ints
    if (tid < 64) {
        int v = (tid < NCHUNK) ? chunksum[tid] : 0;
        int inc = v;
        #pragma unroll
        for (int off = 1; off < 64; off <<= 1) {
            int n = __shfl_up(inc, off, 64);
            if (tid >= off) inc += n;
        }
        if (tid < NCHUNK) s_cb[tid] = inc - v;  // exclusive chunk base
    }
    __syncthreads();
    for (int r = bid * 256 + tid; r < N_NODES; r += gsz) {
        int c8[8], d = 0;
        #pragma unroll
        for (int p8 = 0; p8 < 8; p8++) { c8[p8] = cnt[p8 * NPLANE + r]; d += c8[p8]; }
        int pad = (d + 15) & ~15;
        int s = rowstart[r] + s_cb[r >> 8];
        seg[r] = make_int2(s, s + pad);
        int run = s;
        #pragma unroll
        for (int p8 = 0; p8 < 8; p8++) { cnt[p8 * NPLANE + r] = run; run += c8[p8]; }
        dinv[r] = (d > 0) ? rsqrtf((float)d) : 0.0f;
        sq[r]   = (d > 0) ? sqrtf((float)d) : 0.0f;
        for (int j = d; j < pad; j++) csr_col[s + j] = N_NODES;  // sentinel pad slots
    }
    grid.sync();

    // ---- Phase C: scatter (ALL blocks, same mapping as A -> same XCD plane) ----
    for (int e = bid * 256 + tid; e < E_EDGES; e += gsz) {
        int r = row[e];
        int c = col[e];
        int p = atomicAdd(&mycnt[r], 1);   // XCD-local line, no ping-pong
        csr_col[p] = c;
    }

    // ---- Phase C2: GEMM (blocks 0..G_GEMM-1), bf16 planar h0b pre-scaled by dinv ----
    if (bid >= G_GEMM) return;
    int bx = bid % G_GEMM_X;
    int plane = bid / G_GEMM_X;
    int wave = tid >> 6, lane = tid & 63, quad = lane >> 4, l16 = lane & 15;
    int row0 = bx * 64;
    int n0 = plane * 128;
    unsigned short* h0b_p = h0b + (size_t)plane * (N_NODES + 1) * HALF_CH;

    int ar = tid >> 2;
    int aseg = (tid & 3) * 16;
    int br = tid >> 1;
    int bseg = (tid & 1) * 32;

    f32x4 acc[8] = {};
    for (int k0 = 0; k0 < IN_CH; k0 += 64) {
        {
            int gr = row0 + ar;
            if (gr < N_NODES) {
                const float4* src = (const float4*)(x + (size_t)gr * IN_CH + k0 + aseg);
                #pragma unroll
                for (int i = 0; i < 4; i++) {
                    float4 v = src[i];
                    ushort4 o;
                    o.x = f2b(v.x); o.y = f2b(v.y); o.z = f2b(v.z); o.w = f2b(v.w);
                    *(ushort4*)&As[ar][aseg + i * 4] = o;
                }
            } else {
                ushort4 z = {0, 0, 0, 0};
                #pragma unroll
                for (int i = 0; i < 4; i++) *(ushort4*)&As[ar][aseg + i * 4] = z;
            }
        }
        {
            const float4* src = (const float4*)(w + (size_t)(n0 + br) * IN_CH + k0 + bseg);
            #pragma unroll
            for (int i = 0; i < 8; i++) {
                float4 v = src[i];
                ushort4 o;
                o.x = f2b(v.x); o.y = f2b(v.y); o.z = f2b(v.z); o.w = f2b(v.w);
                *(ushort4*)&Bs[br][bseg + i * 4] = o;
            }
        }
        __syncthreads();
        #pragma unroll
        for (int kk = 0; kk < 2; kk++) {
            bf16x8 a = *(const bf16x8*)&As[wave * 16 + l16][kk * 32 + quad * 8];
            #pragma unroll
            for (int t = 0; t < 8; t++) {
                bf16x8 b = *(const bf16x8*)&Bs[t * 16 + l16][kk * 32 + quad * 8];
                acc[t] = __builtin_amdgcn_mfma_f32_16x16x32_bf16(a, b, acc[t], 0, 0, 0);
            }
        }
        __syncthreads();
    }
    #pragma unroll
    for (int t = 0; t < 8; t++) {
        int lcol = t * 16 + l16;
        int col_ = n0 + lcol;
        float bv = bias[col_];
        #pragma unroll
        for (int r = 0; r < 4; r++) {
            int grow = row0 + wave * 16 + quad * 4 + r;
            if (grow < N_NODES) {
                float v = acc[t][r] + bv;
                h0b_p[(size_t)grow * HALF_CH + lcol] = f2b(v * dinv[grow]);
            }
        }
    }
    // zero the pad row (sentinel gather target) — one block per plane
    if (bx == 0 && tid < 64)
        ((unsigned int*)(h0b_p + (size_t)N_NODES * HALF_CH))[tid] = 0u;
}

// ---------------- SpMM: XCD-plane-partitioned, 4 neighbor rows per VMEM instruction ------
// (unchanged from previous best — verified)
__global__ __launch_bounds__(256) void spmm_kernel(const unsigned short* __restrict__ hb,
                                                   const int2* __restrict__ seg,
                                                   const int* __restrict__ csr_col,
                                                   const float* __restrict__ dinv,
                                                   const float* __restrict__ sq,
                                                   const unsigned short* __restrict__ prev_b,
                                                   const float* __restrict__ wts, int widx,
                                                   unsigned short* __restrict__ yb_out,
                                                   float* __restrict__ axpy_out,
                                                   unsigned short* __restrict__ axpyb_out,
                                                   int n) {
    int plane = blockIdx.x & 1;
    int node = (blockIdx.x >> 1) * 4 + (threadIdx.x >> 6);
    int lane = threadIdx.x & 63;
    if (node >= n) return;
    int sub = lane >> 4, l16 = lane & 15;
    size_t pstride = (size_t)(n + 1) * HALF_CH;
    const unsigned short* hp = hb + (size_t)plane * pstride;

    int2 se = seg[node];
    int s = se.x, e = se.y;
    float acc[8] = {0.f, 0.f, 0.f, 0.f, 0.f, 0.f, 0.f, 0.f};
    if (s < e) {
        int c0 = csr_col[s + 0  + sub];
        int c1 = csr_col[s + 4  + sub];
        int c2 = csr_col[s + 8  + sub];
        int c3 = csr_col[s + 12 + sub];
        int p = s;
        while (true) {
            int pn = p + 16;
            int n0c = csr_col[pn + 0  + sub];   // prefetch next group's cols (slack-safe)
            int n1c = csr_col[pn + 4  + sub];
            int n2c = csr_col[pn + 8  + sub];
            int n3c = csr_col[pn + 12 + sub];
            uint4 v0 = *(const uint4*)(hp + (size_t)c0 * HALF_CH + l16 * 8);
            uint4 v1 = *(const uint4*)(hp + (size_t)c1 * HALF_CH + l16 * 8);
            uint4 v2 = *(const uint4*)(hp + (size_t)c2 * HALF_CH + l16 * 8);
            uint4 v3 = *(const uint4*)(hp + (size_t)c3 * HALF_CH + l16 * 8);
            acc[0] += lo16(v0.x) + lo16(v1.x) + lo16(v2.x) + lo16(v3.x);
            acc[1] += hi16(v0.x) + hi16(v1.x) + hi16(v2.x) + hi16(v3.x);
            acc[2] += lo16(v0.y) + lo16(v1.y) + lo16(v2.y) + lo16(v3.y);
            acc[3] += hi16(v0.y) + hi16(v1.y) + hi16(v2.y) + hi16(v3.y);
            acc[4] += lo16(v0.z) + lo16(v1.z) + lo16(v2.z) + lo16(v3.z);
            acc[5] += hi16(v0.z) + hi16(v1.z) + hi16(v2.z) + hi16(v3.z);
            acc[6] += lo16(v0.w) + lo16(v1.w) + lo16(v2.w) + lo16(v3.w);
            acc[7] += hi16(v0.w) + hi16(v1.w) + hi16(v2.w) + hi16(v3.w);
            c0 = n0c; c1 = n1c; c2 = n2c; c3 = n3c; p = pn;
            if (p >= e) break;
        }
    }
    #pragma unroll
    for (int k = 0; k < 8; k++) {
        acc[k] += __shfl_xor(acc[k], 16, 64);
        acc[k] += __shfl_xor(acc[k], 32, 64);
    }
    if (sub != 0) return;

    float di = dinv[node];
    float y[8];
    #pragma unroll
    for (int k = 0; k < 8; k++) y[k] = di * acc[k];

    size_t pbase = (size_t)plane * pstride + (size_t)node * HALF_CH + l16 * 8;
    size_t padrow = (size_t)plane * pstride + (size_t)n * HALF_CH + l16 * 8;
    if (yb_out) {
        ushort4 o0, o1;
        o0.x = f2b(di * y[0]); o0.y = f2b(di * y[1]); o0.z = f2b(di * y[2]); o0.w = f2b(di * y[3]);
        o1.x = f2b(di * y[4]); o1.y = f2b(di * y[5]); o1.z = f2b(di * y[6]); o1.w = f2b(di * y[7]);
        *(ushort4*)(yb_out + pbase) = o0;
        *(ushort4*)(yb_out + pbase + 4) = o1;
        if (node == 0) {
            ushort4 z = {0, 0, 0, 0};
            *(ushort4*)(yb_out + padrow) = z;
            *(ushort4*)(yb_out + padrow + 4) = z;
        }
    }
    if (prev_b) {
        float wk = wts[widx];
        float sqn = sq[node];
        ushort4 p0 = *(const ushort4*)(prev_b + pbase);
        ushort4 p1 = *(const ushort4*)(prev_b + pbase + 4);
        float o[8];
        o[0] = b2f(p0.x) * sqn + wk * y[0];
        o[1] = b2f(p0.y) * sqn + wk * y[1];
        o[2] = b2f(p0.z) * sqn + wk * y[2];
        o[3] = b2f(p0.w) * sqn + wk * y[3];
        o[4] = b2f(p1.x) * sqn + wk * y[4];
        o[5] = b2f(p1.y) * sqn + wk * y[5];
        o[6] = b2f(p1.z) * sqn + wk * y[6];
        o[7] = b2f(p1.w) * sqn + wk * y[7];
        if (axpy_out) {
            size_t fbase = (size_t)node * OUT_CH + plane * HALF_CH + l16 * 8;
            float4 f0 = {o[0], o[1], o[2], o[3]};
            float4 f1 = {o[4], o[5], o[6], o[7]};
            *(float4*)(axpy_out + fbase) = f0;
            *(float4*)(axpy_out + fbase + 4) = f1;
        }
        if (axpyb_out) {
            ushort4 b0, b1;
            b0.x = f2b(di * o[0]); b0.y = f2b(di * o[1]); b0.z = f2b(di * o[2]); b0.w = f2b(di * o[3]);
            b1.x = f2b(di * o[4]); b1.y = f2b(di * o[5]); b1.z = f2b(di * o[6]); b1.w = f2b(di * o[7]);
            *(ushort4*)(axpyb_out + pbase) = b0;
            *(ushort4*)(axpyb_out + pbase + 4) = b1;
            if (node == 0) {
                ushort4 z = {0, 0, 0, 0};
                *(ushort4*)(axpyb_out + padrow) = z;
                *(ushort4*)(axpyb_out + padrow + 4) = z;
            }
        }
    }
}

extern "C" void kernel_launch(void* const* d_in, const int* in_sizes, int n_in,
                              void* d_out, int out_size, void* d_ws, size_t ws_size,
                              hipStream_t stream) {
    const float* x     = (const float*)d_in[0];
    const int*   ei    = (const int*)d_in[1];   // [2, E]
    const float* lin_w = (const float*)d_in[2]; // [OUT_CH, IN_CH]
    const float* lin_b = (const float*)d_in[3]; // [OUT_CH]
    const float* wts   = (const float*)d_in[4]; // [K]
    float* out = (float*)d_out;

    char* ws = (char*)d_ws;
    size_t off = 0;
    auto alloc = [&](size_t bytes) -> void* {
        void* p = ws + off;
        off += (bytes + 255) & ~(size_t)255;
        return p;
    };
    int*   cnt      = (int*)  alloc((size_t)8 * NPLANE * 4);  // per-XCD count/cursor planes
    int*   rowstart = (int*)  alloc((size_t)N_NODES * 4);
    int*   chunksum = (int*)  alloc((size_t)NCHUNK * 4);
    int2*  seg      = (int2*) alloc((size_t)N_NODES * 8);
    float* dinv     = (float*)alloc(N_NODES * 4);
    float* sq       = (float*)alloc(N_NODES * 4);
    int*   csr_col  = (int*)  alloc((size_t)CSR_CAP * 4);
    unsigned short* h0b   = (unsigned short*)alloc((size_t)2 * (N_NODES + 1) * HALF_CH * 2);
    unsigned short* out1b = (unsigned short*)alloc((size_t)2 * (N_NODES + 1) * HALF_CH * 2);
    unsigned short* t2b   = (unsigned short*)alloc((size_t)2 * (N_NODES + 1) * HALF_CH * 2);

    hipMemsetAsync(cnt, 0, (size_t)8 * NPLANE * 4, stream);

    const int* row = ei;
    const int* col = ei + E_EDGES;

    // Cooperative grid: must be fully co-resident. LDS 27648 B -> 5 blocks/CU -> 1280.
    static int coopGrid = 0;
    if (coopGrid == 0) {
        int dev = 0;
        hipGetDevice(&dev);
        int numCU = 0;
        hipDeviceGetAttribute(&numCU, hipDeviceAttributeMultiprocessorCount, dev);
        int occ = 0;
        hipOccupancyMaxActiveBlocksPerMultiprocessor(&occ, fused_build_gemm, 256, 0);
        long g = (long)occ * (long)numCU;
        if (g > 1280) g = 1280;
        if (g < G_GEMM + NCHUNK) g = G_GEMM + NCHUNK;  // safety floor
        coopGrid = (int)g;
    }

    void* kargs[] = {
        (void*)&x, (void*)&lin_w, (void*)&lin_b, (void*)&row, (void*)&col,
        (void*)&cnt, (void*)&rowstart, (void*)&chunksum,
        (void*)&seg, (void*)&dinv, (void*)&sq, (void*)&csr_col, (void*)&h0b
    };
    hipLaunchCooperativeKernel((void*)fused_build_gemm, dim3(coopGrid), dim3(256),
                               kargs, 0, stream);

    int sgrid = 2 * ((N_NODES + 3) / 4); // plane = bid&1, 4 nodes/block
    // out1b = dinv*(h0 + w0 * spmm(h0)), h0 reconstructed from h0b
    spmm_kernel<<<sgrid, 256, 0, stream>>>(h0b, seg, csr_col, dinv, sq, h0b,
                                           wts, 0, nullptr, nullptr, out1b, N_NODES);
    // t2b = dinv*spmm(out1)
    spmm_kernel<<<sgrid, 256, 0, stream>>>(out1b, seg, csr_col, dinv, sq, nullptr,
                                           wts, 0, t2b, nullptr, nullptr, N_NODES);
    // out = out1 + w1 * spmm(t2), out1 reconstructed from out1b  (fp32 final)
    spmm_kernel<<<sgrid, 256, 0, stream>>>(t2b, seg, csr_col, dinv, sq, out1b,
                                           wts, 1, nullptr, out, nullptr, N_NODES);
}

// Round 2
// 224.006 us; speedup vs baseline: 2.1885x; 2.1885x over previous
//
#include <hip/hip_runtime.h>

#define N_NODES 10000
#define E_EDGES 640000
#define IN_CH   512
#define OUT_CH  256
#define HALF_CH 128
#define CSR_CAP (E_EDGES + 16 * N_NODES + 128)  // padded capacity + prefetch slack
#define G_GEMM_X 157                            // ceil(10000/64)
#define G_GEMM  (G_GEMM_X * 2)                  // x2 planes
#define G_SCAT  625                             // 625*1024 = 640000 edges, 4 edges/thread

typedef short bf16x8 __attribute__((ext_vector_type(8)));
typedef float f32x4  __attribute__((ext_vector_type(4)));

__device__ __forceinline__ unsigned short f2b(float f) {
    unsigned int u = __float_as_uint(f);
    return (unsigned short)((u + 0x7FFFu + ((u >> 16) & 1u)) >> 16);
}
__device__ __forceinline__ float lo16(unsigned int u) { return __uint_as_float(u << 16); }
__device__ __forceinline__ float hi16(unsigned int u) { return __uint_as_float(u & 0xFFFF0000u); }
__device__ __forceinline__ float b2f(unsigned short u) { return __uint_as_float(((unsigned int)u) << 16); }

// ---------------- degree histogram into line-padded slots (cursor32[(r<<5)+1]) ----------------
// One node per 128B line (load-bearing: dense packing measured 9x worse in R1).
// 4 edges/thread: 4 independent atomic chains in flight per thread (latency hiding).
__global__ void deg_kernel(const int* __restrict__ row, int* __restrict__ cursor32, int E) {
    int base = blockIdx.x * 1024 + threadIdx.x;
    int r0 = row[base];
    int r1 = row[base + 256];
    int r2 = row[base + 512];
    int r3 = row[base + 768];
    atomicAdd(&cursor32[(r0 << 5) + 1], 1);
    atomicAdd(&cursor32[(r1 << 5) + 1], 1);
    atomicAdd(&cursor32[(r2 << 5) + 1], 1);
    atomicAdd(&cursor32[(r3 << 5) + 1], 1);
}

// ---------------- order-free segment allocation + dinv/sq + pad-slot sentinels ----------------
// seg[i] = {start, start+padded} (int2, single 8B load in spmm). cursor32[i<<5] = start.
__global__ void alloc_kernel(int* __restrict__ cursor32, int2* __restrict__ seg,
                             float* __restrict__ dinv, float* __restrict__ sq,
                             int* __restrict__ counter, int* __restrict__ csr_col, int n) {
    int i = blockIdx.x * blockDim.x + threadIdx.x;
    if (i >= n) return;
    int d = cursor32[(i << 5) + 1];
    dinv[i] = (d > 0) ? rsqrtf((float)d) : 0.0f;
    sq[i]   = (d > 0) ? sqrtf((float)d) : 0.0f;
    int pad = (d + 15) & ~15;
    int s = atomicAdd(counter, pad);
    seg[i] = make_int2(s, s + pad);
    cursor32[i << 5] = s;
    for (int j = d; j < pad; j++) csr_col[s + j] = N_NODES;
}

// ---------------- fused GEMM (blocks 0..G_GEMM-1) + edge scatter (rest) ----------------
// GEMM writes ONLY bf16 planar h0b pre-scaled by dinv[m] (spmm reconstructs fp32 via sq).
// Scatter: 4 edges/thread — loads batched, then 4 independent atomics, then 4 stores.
__global__ __launch_bounds__(256) void gemm_scatter(const float* __restrict__ x,
                                                    const float* __restrict__ w,
                                                    const float* __restrict__ bias,
                                                    const float* __restrict__ dinv,
                                                    unsigned short* __restrict__ h0b,
                                                    const int* __restrict__ row,
                                                    const int* __restrict__ col,
                                                    int* __restrict__ cursor32,
                                                    int* __restrict__ csr_col) {
    __shared__ unsigned short As[64][72];
    __shared__ unsigned short Bs[128][72];
    int bid = blockIdx.x;
    int tid = threadIdx.x;
    if (bid >= G_GEMM) {
        // ---- scatter path: 4 edges per thread, independent chains ----
        int base = (bid - G_GEMM) * 1024 + tid;
        int r0 = row[base];
        int r1 = row[base + 256];
        int r2 = row[base + 512];
        int r3 = row[base + 768];
        int c0 = col[base];
        int c1 = col[base + 256];
        int c2 = col[base + 512];
        int c3 = col[base + 768];
        int p0 = atomicAdd(&cursor32[r0 << 5], 1);
        int p1 = atomicAdd(&cursor32[r1 << 5], 1);
        int p2 = atomicAdd(&cursor32[r2 << 5], 1);
        int p3 = atomicAdd(&cursor32[r3 << 5], 1);
        csr_col[p0] = c0;
        csr_col[p1] = c1;
        csr_col[p2] = c2;
        csr_col[p3] = c3;
        return;
    }
    // ---- gemm path ----
    int bx = bid % G_GEMM_X;
    int plane = bid / G_GEMM_X;
    int wave = tid >> 6, lane = tid & 63, quad = lane >> 4, l16 = lane & 15;
    int row0 = bx * 64;
    int n0 = plane * 128;
    unsigned short* h0b_p = h0b + (size_t)plane * (N_NODES + 1) * HALF_CH;

    int ar = tid >> 2;
    int aseg = (tid & 3) * 16;
    int br = tid >> 1;
    int bseg = (tid & 1) * 32;

    f32x4 acc[8] = {};
    for (int k0 = 0; k0 < IN_CH; k0 += 64) {
        {
            int gr = row0 + ar;
            if (gr < N_NODES) {
                const float4* src = (const float4*)(x + (size_t)gr * IN_CH + k0 + aseg);
                #pragma unroll
                for (int i = 0; i < 4; i++) {
                    float4 v = src[i];
                    ushort4 o;
                    o.x = f2b(v.x); o.y = f2b(v.y); o.z = f2b(v.z); o.w = f2b(v.w);
                    *(ushort4*)&As[ar][aseg + i * 4] = o;
                }
            } else {
                ushort4 z = {0, 0, 0, 0};
                #pragma unroll
                for (int i = 0; i < 4; i++) *(ushort4*)&As[ar][aseg + i * 4] = z;
            }
        }
        {
            const float4* src = (const float4*)(w + (size_t)(n0 + br) * IN_CH + k0 + bseg);
            #pragma unroll
            for (int i = 0; i < 8; i++) {
                float4 v = src[i];
                ushort4 o;
                o.x = f2b(v.x); o.y = f2b(v.y); o.z = f2b(v.z); o.w = f2b(v.w);
                *(ushort4*)&Bs[br][bseg + i * 4] = o;
            }
        }
        __syncthreads();
        #pragma unroll
        for (int kk = 0; kk < 2; kk++) {
            bf16x8 a = *(const bf16x8*)&As[wave * 16 + l16][kk * 32 + quad * 8];
            #pragma unroll
            for (int t = 0; t < 8; t++) {
                bf16x8 b = *(const bf16x8*)&Bs[t * 16 + l16][kk * 32 + quad * 8];
                acc[t] = __builtin_amdgcn_mfma_f32_16x16x32_bf16(a, b, acc[t], 0, 0, 0);
            }
        }
        __syncthreads();
    }
    #pragma unroll
    for (int t = 0; t < 8; t++) {
        int lcol = t * 16 + l16;
        int col_ = n0 + lcol;
        float bv = bias[col_];
        #pragma unroll
        for (int r = 0; r < 4; r++) {
            int grow = row0 + wave * 16 + quad * 4 + r;
            if (grow < N_NODES) {
                float v = acc[t][r] + bv;
                h0b_p[(size_t)grow * HALF_CH + lcol] = f2b(v * dinv[grow]);
            }
        }
    }
    // zero the pad row (sentinel gather target) — one block per plane
    if (bx == 0 && tid < 64)
        ((unsigned int*)(h0b_p + (size_t)N_NODES * HALF_CH))[tid] = 0u;
}

// ---------------- SpMM: XCD-plane-partitioned, 4 neighbor rows per VMEM instruction ------
// plane = blockIdx&1 (all 4 waves of a block on the same plane). sub = lane>>4 picks the
// edge in a quad, l16 picks 16B of the 256B row. seg int2 = {start, padded end}.
// prev reconstructed from dinv-pre-scaled bf16: prev = b2f(prev_b) * sq[node].
__global__ __launch_bounds__(256) void spmm_kernel(const unsigned short* __restrict__ hb,
                                                   const int2* __restrict__ seg,
                                                   const int* __restrict__ csr_col,
                                                   const float* __restrict__ dinv,
                                                   const float* __restrict__ sq,
                                                   const unsigned short* __restrict__ prev_b,
                                                   const float* __restrict__ wts, int widx,
                                                   unsigned short* __restrict__ yb_out,
                                                   float* __restrict__ axpy_out,
                                                   unsigned short* __restrict__ axpyb_out,
                                                   int n) {
    int plane = blockIdx.x & 1;
    int node = (blockIdx.x >> 1) * 4 + (threadIdx.x >> 6);
    int lane = threadIdx.x & 63;
    if (node >= n) return;
    int sub = lane >> 4, l16 = lane & 15;
    size_t pstride = (size_t)(n + 1) * HALF_CH;
    const unsigned short* hp = hb + (size_t)plane * pstride;

    int2 se = seg[node];
    int s = se.x, e = se.y;
    float acc[8] = {0.f, 0.f, 0.f, 0.f, 0.f, 0.f, 0.f, 0.f};
    if (s < e) {
        int c0 = csr_col[s + 0  + sub];
        int c1 = csr_col[s + 4  + sub];
        int c2 = csr_col[s + 8  + sub];
        int c3 = csr_col[s + 12 + sub];
        int p = s;
        while (true) {
            int pn = p + 16;
            int n0c = csr_col[pn + 0  + sub];   // prefetch next group's cols (slack-safe)
            int n1c = csr_col[pn + 4  + sub];
            int n2c = csr_col[pn + 8  + sub];
            int n3c = csr_col[pn + 12 + sub];
            uint4 v0 = *(const uint4*)(hp + (size_t)c0 * HALF_CH + l16 * 8);
            uint4 v1 = *(const uint4*)(hp + (size_t)c1 * HALF_CH + l16 * 8);
            uint4 v2 = *(const uint4*)(hp + (size_t)c2 * HALF_CH + l16 * 8);
            uint4 v3 = *(const uint4*)(hp + (size_t)c3 * HALF_CH + l16 * 8);
            acc[0] += lo16(v0.x) + lo16(v1.x) + lo16(v2.x) + lo16(v3.x);
            acc[1] += hi16(v0.x) + hi16(v1.x) + hi16(v2.x) + hi16(v3.x);
            acc[2] += lo16(v0.y) + lo16(v1.y) + lo16(v2.y) + lo16(v3.y);
            acc[3] += hi16(v0.y) + hi16(v1.y) + hi16(v2.y) + hi16(v3.y);
            acc[4] += lo16(v0.z) + lo16(v1.z) + lo16(v2.z) + lo16(v3.z);
            acc[5] += hi16(v0.z) + hi16(v1.z) + hi16(v2.z) + hi16(v3.z);
            acc[6] += lo16(v0.w) + lo16(v1.w) + lo16(v2.w) + lo16(v3.w);
            acc[7] += hi16(v0.w) + hi16(v1.w) + hi16(v2.w) + hi16(v3.w);
            c0 = n0c; c1 = n1c; c2 = n2c; c3 = n3c; p = pn;
            if (p >= e) break;
        }
    }
    #pragma unroll
    for (int k = 0; k < 8; k++) {
        acc[k] += __shfl_xor(acc[k], 16, 64);
        acc[k] += __shfl_xor(acc[k], 32, 64);
    }
    if (sub != 0) return;

    float di = dinv[node];
    float y[8];
    #pragma unroll
    for (int k = 0; k < 8; k++) y[k] = di * acc[k];

    size_t pbase = (size_t)plane * pstride + (size_t)node * HALF_CH + l16 * 8;
    size_t padrow = (size_t)plane * pstride + (size_t)n * HALF_CH + l16 * 8;
    if (yb_out) {
        ushort4 o0, o1;
        o0.x = f2b(di * y[0]); o0.y = f2b(di * y[1]); o0.z = f2b(di * y[2]); o0.w = f2b(di * y[3]);
        o1.x = f2b(di * y[4]); o1.y = f2b(di * y[5]); o1.z = f2b(di * y[6]); o1.w = f2b(di * y[7]);
        *(ushort4*)(yb_out + pbase) = o0;
        *(ushort4*)(yb_out + pbase + 4) = o1;
        if (node == 0) {
            ushort4 z = {0, 0, 0, 0};
            *(ushort4*)(yb_out + padrow) = z;
            *(ushort4*)(yb_out + padrow + 4) = z;
        }
    }
    if (prev_b) {
        float wk = wts[widx];
        float sqn = sq[node];
        ushort4 p0 = *(const ushort4*)(prev_b + pbase);
        ushort4 p1 = *(const ushort4*)(prev_b + pbase + 4);
        float o[8];
        o[0] = b2f(p0.x) * sqn + wk * y[0];
        o[1] = b2f(p0.y) * sqn + wk * y[1];
        o[2] = b2f(p0.z) * sqn + wk * y[2];
        o[3] = b2f(p0.w) * sqn + wk * y[3];
        o[4] = b2f(p1.x) * sqn + wk * y[4];
        o[5] = b2f(p1.y) * sqn + wk * y[5];
        o[6] = b2f(p1.z) * sqn + wk * y[6];
        o[7] = b2f(p1.w) * sqn + wk * y[7];
        if (axpy_out) {
            size_t fbase = (size_t)node * OUT_CH + plane * HALF_CH + l16 * 8;
            float4 f0 = {o[0], o[1], o[2], o[3]};
            float4 f1 = {o[4], o[5], o[6], o[7]};
            *(float4*)(axpy_out + fbase) = f0;
            *(float4*)(axpy_out + fbase + 4) = f1;
        }
        if (axpyb_out) {
            ushort4 b0, b1;
            b0.x = f2b(di * o[0]); b0.y = f2b(di * o[1]); b0.z = f2b(di * o[2]); b0.w = f2b(di * o[3]);
            b1.x = f2b(di * o[4]); b1.y = f2b(di * o[5]); b1.z = f2b(di * o[6]); b1.w = f2b(di * o[7]);
            *(ushort4*)(axpyb_out + pbase) = b0;
            *(ushort4*)(axpyb_out + pbase + 4) = b1;
            if (node == 0) {
                ushort4 z = {0, 0, 0, 0};
                *(ushort4*)(axpyb_out + padrow) = z;
                *(ushort4*)(axpyb_out + padrow + 4) = z;
            }
        }
    }
}

extern "C" void kernel_launch(void* const* d_in, const int* in_sizes, int n_in,
                              void* d_out, int out_size, void* d_ws, size_t ws_size,
                              hipStream_t stream) {
    const float* x     = (const float*)d_in[0];
    const int*   ei    = (const int*)d_in[1];   // [2, E]
    const float* lin_w = (const float*)d_in[2]; // [OUT_CH, IN_CH]
    const float* lin_b = (const float*)d_in[3]; // [OUT_CH]
    const float* wts   = (const float*)d_in[4]; // [K]
    float* out = (float*)d_out;

    char* ws = (char*)d_ws;
    size_t off = 0;
    auto alloc = [&](size_t bytes) -> void* {
        void* p = ws + off;
        off += (bytes + 255) & ~(size_t)255;
        return p;
    };
    // cursor32: line-padded; slot +0 = scatter cursor, slot +1 = degree. +1 line for counter.
    int*   cursor32 = (int*)  alloc(((size_t)N_NODES * 32 + 32) * 4);
    int*   counter  = cursor32 + (size_t)N_NODES * 32;
    int2*  seg      = (int2*) alloc((size_t)N_NODES * 8);
    float* dinv     = (float*)alloc(N_NODES * 4);
    float* sq       = (float*)alloc(N_NODES * 4);
    int*   csr_col  = (int*)  alloc((size_t)CSR_CAP * 4);
    unsigned short* h0b   = (unsigned short*)alloc((size_t)2 * (N_NODES + 1) * HALF_CH * 2);
    unsigned short* out1b = (unsigned short*)alloc((size_t)2 * (N_NODES + 1) * HALF_CH * 2);
    unsigned short* t2b   = (unsigned short*)alloc((size_t)2 * (N_NODES + 1) * HALF_CH * 2);

    hipMemsetAsync(cursor32, 0, ((size_t)N_NODES * 32 + 32) * 4, stream);

    const int* row = ei;
    const int* col = ei + E_EDGES;

    deg_kernel<<<E_EDGES / 1024, 256, 0, stream>>>(row, cursor32, E_EDGES);
    alloc_kernel<<<(N_NODES + 255) / 256, 256, 0, stream>>>(cursor32, seg, dinv, sq,
                                                            counter, csr_col, N_NODES);

    // fused: GEMM (h0b bf16 planar pre-scaled only) || CSR scatter (4 edges/thread)
    gemm_scatter<<<G_GEMM + G_SCAT, 256, 0, stream>>>(x, lin_w, lin_b, dinv, h0b,
                                                      row, col, cursor32, csr_col);

    int sgrid = 2 * ((N_NODES + 3) / 4); // plane = bid&1, 4 nodes/block
    // out1b = dinv*(h0 + w0 * spmm(h0)), h0 reconstructed from h0b
    spmm_kernel<<<sgrid, 256, 0, stream>>>(h0b, seg, csr_col, dinv, sq, h0b,
                                           wts, 0, nullptr, nullptr, out1b, N_NODES);
    // t2b = dinv*spmm(out1)
    spmm_kernel<<<sgrid, 256, 0, stream>>>(out1b, seg, csr_col, dinv, sq, nullptr,
                                           wts, 0, t2b, nullptr, nullptr, N_NODES);
    // out = out1 + w1 * spmm(t2), out1 reconstructed from out1b  (fp32 final)
    spmm_kernel<<<sgrid, 256, 0, stream>>>(t2b, seg, csr_col, dinv, sq, out1b,
                                           wts, 1, nullptr, out, nullptr, N_NODES);
}

// Round 3
// 200.207 us; speedup vs baseline: 2.4486x; 1.1189x over previous
//
#include <hip/hip_runtime.h>

#define N_NODES 10000
#define E_EDGES 640000
#define IN_CH   512
#define OUT_CH  256
#define HALF_CH 128
#define CSR_CAP (E_EDGES + 16 * N_NODES + 128)  // padded capacity + prefetch slack
#define G_GEMM_X 157                            // ceil(10000/64)
#define G_GEMM  (G_GEMM_X * 2)                  // x2 planes
#define HBLK    125                             // histogram/scatter chunks
#define EPB     5120                            // edges per chunk: 125*5120 = 640000

typedef short bf16x8 __attribute__((ext_vector_type(8)));
typedef float f32x4  __attribute__((ext_vector_type(4)));

__device__ __forceinline__ unsigned short f2b(float f) {
    unsigned int u = __float_as_uint(f);
    return (unsigned short)((u + 0x7FFFu + ((u >> 16) & 1u)) >> 16);
}
__device__ __forceinline__ float lo16(unsigned int u) { return __uint_as_float(u << 16); }
__device__ __forceinline__ float hi16(unsigned int u) { return __uint_as_float(u & 0xFFFF0000u); }
__device__ __forceinline__ float b2f(unsigned short u) { return __uint_as_float(((unsigned int)u) << 16); }

// ---------------- LDS-histogram rank pass: NO global atomics ----------------
// Block b owns edges [b*EPB, (b+1)*EPB). LDS atomicAdd return = within-block rank.
// Partial counts cnt[b][r] written dense+coalesced (no RMW on global lines at all).
__global__ __launch_bounds__(256) void hist_rank(const int* __restrict__ row,
                                                 int* __restrict__ cnt,          // [HBLK][N]
                                                 unsigned short* __restrict__ rank) {
    __shared__ int hist[N_NODES];
    int b = blockIdx.x, tid = threadIdx.x;
    for (int i = tid; i < N_NODES; i += 256) hist[i] = 0;
    __syncthreads();
    int ebase = b * EPB;
    #pragma unroll 4
    for (int i = tid; i < EPB; i += 256) {
        int r = row[ebase + i];
        rank[ebase + i] = (unsigned short)atomicAdd(&hist[r], 1);
    }
    __syncthreads();
    int* cb = cnt + (size_t)b * N_NODES;
    for (int i = tid; i < N_NODES; i += 256) cb[i] = hist[i];
}

// ---------------- allocation: degree sum, seg assignment, in-place block bases ----------
// counter atomic is uniform-address -> wave-combined by compiler (cheap, order-free).
// cnt[b][r] is converted IN PLACE to the exclusive per-block base for the scatter.
__global__ void alloc2(int* __restrict__ cnt,            // [HBLK][N] counts -> bases
                       int2* __restrict__ seg,
                       float* __restrict__ dinv, float* __restrict__ sq,
                       int* __restrict__ counter, int* __restrict__ csr_col, int n) {
    int r = blockIdx.x * blockDim.x + threadIdx.x;
    if (r >= n) return;
    int d = 0;
    for (int b = 0; b < HBLK; b++) d += cnt[(size_t)b * N_NODES + r];
    dinv[r] = (d > 0) ? rsqrtf((float)d) : 0.0f;
    sq[r]   = (d > 0) ? sqrtf((float)d) : 0.0f;
    int pad = (d + 15) & ~15;
    int s = atomicAdd(counter, pad);
    seg[r] = make_int2(s, s + pad);
    int run = s;
    for (int b = 0; b < HBLK; b++) {
        int c = cnt[(size_t)b * N_NODES + r];
        cnt[(size_t)b * N_NODES + r] = run;   // exclusive base for block b, row r
        run += c;
    }
    for (int j = d; j < pad; j++) csr_col[s + j] = N_NODES;  // sentinel pad slots
}

// ---------------- fused GEMM (blocks 0..G_GEMM-1) + atomic-free scatter (rest) ----------
__global__ __launch_bounds__(256) void gemm_scatter(const float* __restrict__ x,
                                                    const float* __restrict__ w,
                                                    const float* __restrict__ bias,
                                                    const float* __restrict__ dinv,
                                                    unsigned short* __restrict__ h0b,
                                                    const int* __restrict__ row,
                                                    const int* __restrict__ col,
                                                    const int* __restrict__ base,   // [HBLK][N]
                                                    const unsigned short* __restrict__ rank,
                                                    int* __restrict__ csr_col) {
    __shared__ unsigned short As[64][72];
    __shared__ unsigned short Bs[128][72];
    int bid = blockIdx.x;
    int tid = threadIdx.x;
    if (bid >= G_GEMM) {
        // ---- scatter path: same chunking as hist_rank; pure loads + 1 store/edge ----
        int sb = bid - G_GEMM;
        const int* bb = base + (size_t)sb * N_NODES;
        int ebase = sb * EPB;
        #pragma unroll 4
        for (int i = tid; i < EPB; i += 256) {
            int e = ebase + i;
            int r = row[e];
            int p = bb[r] + (int)rank[e];
            csr_col[p] = col[e];
        }
        return;
    }
    // ---- gemm path (unchanged, verified) ----
    int bx = bid % G_GEMM_X;
    int plane = bid / G_GEMM_X;
    int wave = tid >> 6, lane = tid & 63, quad = lane >> 4, l16 = lane & 15;
    int row0 = bx * 64;
    int n0 = plane * 128;
    unsigned short* h0b_p = h0b + (size_t)plane * (N_NODES + 1) * HALF_CH;

    int ar = tid >> 2;
    int aseg = (tid & 3) * 16;
    int br = tid >> 1;
    int bseg = (tid & 1) * 32;

    f32x4 acc[8] = {};
    for (int k0 = 0; k0 < IN_CH; k0 += 64) {
        {
            int gr = row0 + ar;
            if (gr < N_NODES) {
                const float4* src = (const float4*)(x + (size_t)gr * IN_CH + k0 + aseg);
                #pragma unroll
                for (int i = 0; i < 4; i++) {
                    float4 v = src[i];
                    ushort4 o;
                    o.x = f2b(v.x); o.y = f2b(v.y); o.z = f2b(v.z); o.w = f2b(v.w);
                    *(ushort4*)&As[ar][aseg + i * 4] = o;
                }
            } else {
                ushort4 z = {0, 0, 0, 0};
                #pragma unroll
                for (int i = 0; i < 4; i++) *(ushort4*)&As[ar][aseg + i * 4] = z;
            }
        }
        {
            const float4* src = (const float4*)(w + (size_t)(n0 + br) * IN_CH + k0 + bseg);
            #pragma unroll
            for (int i = 0; i < 8; i++) {
                float4 v = src[i];
                ushort4 o;
                o.x = f2b(v.x); o.y = f2b(v.y); o.z = f2b(v.z); o.w = f2b(v.w);
                *(ushort4*)&Bs[br][bseg + i * 4] = o;
            }
        }
        __syncthreads();
        #pragma unroll
        for (int kk = 0; kk < 2; kk++) {
            bf16x8 a = *(const bf16x8*)&As[wave * 16 + l16][kk * 32 + quad * 8];
            #pragma unroll
            for (int t = 0; t < 8; t++) {
                bf16x8 b = *(const bf16x8*)&Bs[t * 16 + l16][kk * 32 + quad * 8];
                acc[t] = __builtin_amdgcn_mfma_f32_16x16x32_bf16(a, b, acc[t], 0, 0, 0);
            }
        }
        __syncthreads();
    }
    #pragma unroll
    for (int t = 0; t < 8; t++) {
        int lcol = t * 16 + l16;
        int col_ = n0 + lcol;
        float bv = bias[col_];
        #pragma unroll
        for (int r = 0; r < 4; r++) {
            int grow = row0 + wave * 16 + quad * 4 + r;
            if (grow < N_NODES) {
                float v = acc[t][r] + bv;
                h0b_p[(size_t)grow * HALF_CH + lcol] = f2b(v * dinv[grow]);
            }
        }
    }
    // zero the pad row (sentinel gather target) — one block per plane
    if (bx == 0 && tid < 64)
        ((unsigned int*)(h0b_p + (size_t)N_NODES * HALF_CH))[tid] = 0u;
}

// ---------------- SpMM: XCD-plane-partitioned, 4 neighbor rows per VMEM instruction ------
// (unchanged from verified baseline)
__global__ __launch_bounds__(256) void spmm_kernel(const unsigned short* __restrict__ hb,
                                                   const int2* __restrict__ seg,
                                                   const int* __restrict__ csr_col,
                                                   const float* __restrict__ dinv,
                                                   const float* __restrict__ sq,
                                                   const unsigned short* __restrict__ prev_b,
                                                   const float* __restrict__ wts, int widx,
                                                   unsigned short* __restrict__ yb_out,
                                                   float* __restrict__ axpy_out,
                                                   unsigned short* __restrict__ axpyb_out,
                                                   int n) {
    int plane = blockIdx.x & 1;
    int node = (blockIdx.x >> 1) * 4 + (threadIdx.x >> 6);
    int lane = threadIdx.x & 63;
    if (node >= n) return;
    int sub = lane >> 4, l16 = lane & 15;
    size_t pstride = (size_t)(n + 1) * HALF_CH;
    const unsigned short* hp = hb + (size_t)plane * pstride;

    int2 se = seg[node];
    int s = se.x, e = se.y;
    float acc[8] = {0.f, 0.f, 0.f, 0.f, 0.f, 0.f, 0.f, 0.f};
    if (s < e) {
        int c0 = csr_col[s + 0  + sub];
        int c1 = csr_col[s + 4  + sub];
        int c2 = csr_col[s + 8  + sub];
        int c3 = csr_col[s + 12 + sub];
        int p = s;
        while (true) {
            int pn = p + 16;
            int n0c = csr_col[pn + 0  + sub];   // prefetch next group's cols (slack-safe)
            int n1c = csr_col[pn + 4  + sub];
            int n2c = csr_col[pn + 8  + sub];
            int n3c = csr_col[pn + 12 + sub];
            uint4 v0 = *(const uint4*)(hp + (size_t)c0 * HALF_CH + l16 * 8);
            uint4 v1 = *(const uint4*)(hp + (size_t)c1 * HALF_CH + l16 * 8);
            uint4 v2 = *(const uint4*)(hp + (size_t)c2 * HALF_CH + l16 * 8);
            uint4 v3 = *(const uint4*)(hp + (size_t)c3 * HALF_CH + l16 * 8);
            acc[0] += lo16(v0.x) + lo16(v1.x) + lo16(v2.x) + lo16(v3.x);
            acc[1] += hi16(v0.x) + hi16(v1.x) + hi16(v2.x) + hi16(v3.x);
            acc[2] += lo16(v0.y) + lo16(v1.y) + lo16(v2.y) + lo16(v3.y);
            acc[3] += hi16(v0.y) + hi16(v1.y) + hi16(v2.y) + hi16(v3.y);
            acc[4] += lo16(v0.z) + lo16(v1.z) + lo16(v2.z) + lo16(v3.z);
            acc[5] += hi16(v0.z) + hi16(v1.z) + hi16(v2.z) + hi16(v3.z);
            acc[6] += lo16(v0.w) + lo16(v1.w) + lo16(v2.w) + lo16(v3.w);
            acc[7] += hi16(v0.w) + hi16(v1.w) + hi16(v2.w) + hi16(v3.w);
            c0 = n0c; c1 = n1c; c2 = n2c; c3 = n3c; p = pn;
            if (p >= e) break;
        }
    }
    #pragma unroll
    for (int k = 0; k < 8; k++) {
        acc[k] += __shfl_xor(acc[k], 16, 64);
        acc[k] += __shfl_xor(acc[k], 32, 64);
    }
    if (sub != 0) return;

    float di = dinv[node];
    float y[8];
    #pragma unroll
    for (int k = 0; k < 8; k++) y[k] = di * acc[k];

    size_t pbase = (size_t)plane * pstride + (size_t)node * HALF_CH + l16 * 8;
    size_t padrow = (size_t)plane * pstride + (size_t)n * HALF_CH + l16 * 8;
    if (yb_out) {
        ushort4 o0, o1;
        o0.x = f2b(di * y[0]); o0.y = f2b(di * y[1]); o0.z = f2b(di * y[2]); o0.w = f2b(di * y[3]);
        o1.x = f2b(di * y[4]); o1.y = f2b(di * y[5]); o1.z = f2b(di * y[6]); o1.w = f2b(di * y[7]);
        *(ushort4*)(yb_out + pbase) = o0;
        *(ushort4*)(yb_out + pbase + 4) = o1;
        if (node == 0) {
            ushort4 z = {0, 0, 0, 0};
            *(ushort4*)(yb_out + padrow) = z;
            *(ushort4*)(yb_out + padrow + 4) = z;
        }
    }
    if (prev_b) {
        float wk = wts[widx];
        float sqn = sq[node];
        ushort4 p0 = *(const ushort4*)(prev_b + pbase);
        ushort4 p1 = *(const ushort4*)(prev_b + pbase + 4);
        float o[8];
        o[0] = b2f(p0.x) * sqn + wk * y[0];
        o[1] = b2f(p0.y) * sqn + wk * y[1];
        o[2] = b2f(p0.z) * sqn + wk * y[2];
        o[3] = b2f(p0.w) * sqn + wk * y[3];
        o[4] = b2f(p1.x) * sqn + wk * y[4];
        o[5] = b2f(p1.y) * sqn + wk * y[5];
        o[6] = b2f(p1.z) * sqn + wk * y[6];
        o[7] = b2f(p1.w) * sqn + wk * y[7];
        if (axpy_out) {
            size_t fbase = (size_t)node * OUT_CH + plane * HALF_CH + l16 * 8;
            float4 f0 = {o[0], o[1], o[2], o[3]};
            float4 f1 = {o[4], o[5], o[6], o[7]};
            *(float4*)(axpy_out + fbase) = f0;
            *(float4*)(axpy_out + fbase + 4) = f1;
        }
        if (axpyb_out) {
            ushort4 b0, b1;
            b0.x = f2b(di * o[0]); b0.y = f2b(di * o[1]); b0.z = f2b(di * o[2]); b0.w = f2b(di * o[3]);
            b1.x = f2b(di * o[4]); b1.y = f2b(di * o[5]); b1.z = f2b(di * o[6]); b1.w = f2b(di * o[7]);
            *(ushort4*)(axpyb_out + pbase) = b0;
            *(ushort4*)(axpyb_out + pbase + 4) = b1;
            if (node == 0) {
                ushort4 z = {0, 0, 0, 0};
                *(ushort4*)(axpyb_out + padrow) = z;
                *(ushort4*)(axpyb_out + padrow + 4) = z;
            }
        }
    }
}

extern "C" void kernel_launch(void* const* d_in, const int* in_sizes, int n_in,
                              void* d_out, int out_size, void* d_ws, size_t ws_size,
                              hipStream_t stream) {
    const float* x     = (const float*)d_in[0];
    const int*   ei    = (const int*)d_in[1];   // [2, E]
    const float* lin_w = (const float*)d_in[2]; // [OUT_CH, IN_CH]
    const float* lin_b = (const float*)d_in[3]; // [OUT_CH]
    const float* wts   = (const float*)d_in[4]; // [K]
    float* out = (float*)d_out;

    char* ws = (char*)d_ws;
    size_t off = 0;
    auto alloc = [&](size_t bytes) -> void* {
        void* p = ws + off;
        off += (bytes + 255) & ~(size_t)255;
        return p;
    };
    int*   cnt      = (int*)  alloc((size_t)HBLK * N_NODES * 4);  // counts -> bases (in place)
    unsigned short* rank = (unsigned short*)alloc((size_t)E_EDGES * 2);
    int*   counter  = (int*)  alloc(256);
    int2*  seg      = (int2*) alloc((size_t)N_NODES * 8);
    float* dinv     = (float*)alloc(N_NODES * 4);
    float* sq       = (float*)alloc(N_NODES * 4);
    int*   csr_col  = (int*)  alloc((size_t)CSR_CAP * 4);
    unsigned short* h0b   = (unsigned short*)alloc((size_t)2 * (N_NODES + 1) * HALF_CH * 2);
    unsigned short* out1b = (unsigned short*)alloc((size_t)2 * (N_NODES + 1) * HALF_CH * 2);
    unsigned short* t2b   = (unsigned short*)alloc((size_t)2 * (N_NODES + 1) * HALF_CH * 2);

    hipMemsetAsync(counter, 0, 4, stream);

    const int* row = ei;
    const int* col = ei + E_EDGES;

    hist_rank<<<HBLK, 256, 0, stream>>>(row, cnt, rank);
    alloc2<<<(N_NODES + 255) / 256, 256, 0, stream>>>(cnt, seg, dinv, sq,
                                                      counter, csr_col, N_NODES);

    // fused: GEMM (h0b bf16 planar pre-scaled only) || atomic-free CSR scatter
    gemm_scatter<<<G_GEMM + HBLK, 256, 0, stream>>>(x, lin_w, lin_b, dinv, h0b,
                                                    row, col, cnt, rank, csr_col);

    int sgrid = 2 * ((N_NODES + 3) / 4); // plane = bid&1, 4 nodes/block
    // out1b = dinv*(h0 + w0 * spmm(h0)), h0 reconstructed from h0b
    spmm_kernel<<<sgrid, 256, 0, stream>>>(h0b, seg, csr_col, dinv, sq, h0b,
                                           wts, 0, nullptr, nullptr, out1b, N_NODES);
    // t2b = dinv*spmm(out1)
    spmm_kernel<<<sgrid, 256, 0, stream>>>(out1b, seg, csr_col, dinv, sq, nullptr,
                                           wts, 0, t2b, nullptr, nullptr, N_NODES);
    // out = out1 + w1 * spmm(t2), out1 reconstructed from out1b  (fp32 final)
    spmm_kernel<<<sgrid, 256, 0, stream>>>(t2b, seg, csr_col, dinv, sq, out1b,
                                           wts, 1, nullptr, out, nullptr, N_NODES);
}